// Round 5
// baseline (76.216 us; speedup 1.0000x reference)
//
#include <hip/hip_runtime.h>

#define IMG_H 512
#define IMG_W 512
#define NIMG  32
#define RPW   4                      // output rows per wave
#define NWAVE 4                      // waves per block
#define ROWS_PER_BLOCK (RPW * NWAVE) // 16
#define STRIPS (IMG_H / ROWS_PER_BLOCK) // 32 strips per image
#define NBLK (NIMG * STRIPS)         // 1024 blocks

__device__ __forceinline__ float sh_up(float v, int lane) {
    float t = __shfl_up(v, 1, 64);
    return lane == 0 ? 0.f : t;
}
__device__ __forceinline__ float sh_dn(float v, int lane) {
    float t = __shfl_down(v, 1, 64);
    return lane == 63 ? 0.f : t;
}

// load one row's 8 columns for this lane (zeros outside the image)
__device__ __forceinline__ void rowvals(const float* __restrict__ p, int y, float* x) {
    if ((unsigned)y < (unsigned)IMG_H) {
        const float4* q = (const float4*)(p + (size_t)y * IMG_W);
        float4 a = q[0], b = q[1];
        x[0] = a.x; x[1] = a.y; x[2] = a.z; x[3] = a.w;
        x[4] = b.x; x[5] = b.y; x[6] = b.z; x[7] = b.w;
    } else {
        #pragma unroll
        for (int k = 0; k < 8; ++k) x[k] = 0.f;
    }
}

__device__ __forceinline__ void accrow(const float* x1, const float* x2,
        float* s1, float* s2, float* s11, float* s22, float* s12) {
    #pragma unroll
    for (int k = 0; k < 8; ++k) {
        s1[k] += x1[k]; s2[k] += x2[k];
        s11[k] = fmaf(x1[k], x1[k], s11[k]);
        s22[k] = fmaf(x2[k], x2[k], s22[k]);
        s12[k] = fmaf(x1[k], x2[k], s12[k]);
    }
}
__device__ __forceinline__ void subrow(const float* x1, const float* x2,
        float* s1, float* s2, float* s11, float* s22, float* s12) {
    #pragma unroll
    for (int k = 0; k < 8; ++k) {
        s1[k] -= x1[k]; s2[k] -= x2[k];
        s11[k] = fmaf(-x1[k], x1[k], s11[k]);
        s22[k] = fmaf(-x2[k], x2[k], s22[k]);
        s12[k] = fmaf(-x1[k], x2[k], s12[k]);
    }
}

// horizontal 7-box-sum: v[0..7] = this lane's 8 column values (vertical sums),
// halo via lane+-1 shuffles, sliding-window in registers.
__device__ __forceinline__ void hbox(const float* v, float* h, int lane) {
    float l5 = sh_up(v[5], lane), l6 = sh_up(v[6], lane), l7 = sh_up(v[7], lane);
    float r0 = sh_dn(v[0], lane), r1 = sh_dn(v[1], lane), r2 = sh_dn(v[2], lane);
    h[0] = ((l5 + l6) + (l7 + v[0])) + ((v[1] + v[2]) + v[3]);
    h[1] = h[0] - l5   + v[4];
    h[2] = h[1] - l6   + v[5];
    h[3] = h[2] - l7   + v[6];
    h[4] = h[3] - v[0] + v[7];
    h[5] = h[4] - v[1] + r0;
    h[6] = h[5] - v[2] + r1;
    h[7] = h[6] - v[3] + r2;
}

// one output row: horizontal sums + SSIM formula, returns partial sum
__device__ __forceinline__ float rowssim(const float* s1, const float* s2,
        const float* s11, const float* s22, const float* s12, int lane) {
    constexpr float C1f = 1e-4f;   // (0.01)^2
    constexpr float C2f = 9e-4f;   // (0.03)^2
    float h1[8], h2[8], h11[8], h22[8], h12[8];
    hbox(s1,  h1,  lane);
    hbox(s2,  h2,  lane);
    hbox(s11, h11, lane);
    hbox(s22, h22, lane);
    hbox(s12, h12, lane);
    float acc = 0.f;
    #pragma unroll
    for (int k = 0; k < 8; ++k) {
        const float mu1 = h1[k], mu2 = h2[k];
        const float mu11 = mu1 * mu1, mu22 = mu2 * mu2, mu12 = mu1 * mu2;
        const float sg1  = h11[k] - mu11;
        const float sg2  = h22[k] - mu22;
        const float sg12 = h12[k] - mu12;
        const float num = (2.f * mu12 + C1f) * (2.f * sg12 + C2f);
        const float den = (mu11 + mu22 + C1f) * (sg1 + sg2 + C2f);
        float r = __builtin_amdgcn_rcpf(den);
        r = r * (2.0f - den * r);          // den > 0 always; 1 Newton step
        acc = fmaf(num, r, acc);
    }
    return acc;
}

extern "C" __global__ void __launch_bounds__(256, 3)
ssim_main(const float* __restrict__ img1, const float* __restrict__ img2,
          float* __restrict__ partials)
{
    const int tid  = threadIdx.x;
    const int lane = tid & 63;
    const int wv   = tid >> 6;

    // XCD-aware swizzle: 1024 blocks, 8 XCDs -> each XCD gets 4 whole images
    const int bid   = blockIdx.x;
    const int xcd   = bid & 7;
    const int idx   = bid >> 3;           // 0..127
    const int img   = xcd * (NIMG / 8) + (idx >> 5);
    const int strip = idx & 31;
    const int wy0   = strip * ROWS_PER_BLOCK + wv * RPW;

    const size_t base = (size_t)img * (IMG_H * IMG_W) + (size_t)(lane << 3);
    const float* p1 = img1 + base;
    const float* p2 = img2 + base;

    float s1[8], s2[8], s11[8], s22[8], s12[8];
    #pragma unroll
    for (int k = 0; k < 8; ++k) { s1[k] = s2[k] = s11[k] = s22[k] = s12[k] = 0.f; }

    // Hand software-pipeline: two rotating load buffers (a,b) + leave buffer (c).
    // Every load issue sits one accumulate (or a whole rowssim) ahead of its
    // consume, so L2/L3 latency hides under VALU work.
    float a1[8], a2[8], b1[8], b2[8], c1[8], c2[8];

    // rows r0..r9 = wy0-3 .. wy0+6; leave rows r0..r2 re-loaded (L1/L2 hot)
    rowvals(p1, wy0 - 3, a1); rowvals(p2, wy0 - 3, a2);   // r0 -> a
    rowvals(p1, wy0 - 2, b1); rowvals(p2, wy0 - 2, b2);   // r1 -> b

    accrow(a1, a2, s1, s2, s11, s22, s12);                 // +r0
    rowvals(p1, wy0 - 1, a1); rowvals(p2, wy0 - 1, a2);   // r2 -> a
    accrow(b1, b2, s1, s2, s11, s22, s12);                 // +r1
    rowvals(p1, wy0 + 0, b1); rowvals(p2, wy0 + 0, b2);   // r3 -> b
    accrow(a1, a2, s1, s2, s11, s22, s12);                 // +r2
    rowvals(p1, wy0 + 1, a1); rowvals(p2, wy0 + 1, a2);   // r4 -> a
    accrow(b1, b2, s1, s2, s11, s22, s12);                 // +r3
    rowvals(p1, wy0 + 2, b1); rowvals(p2, wy0 + 2, b2);   // r5 -> b
    accrow(a1, a2, s1, s2, s11, s22, s12);                 // +r4
    rowvals(p1, wy0 + 3, a1); rowvals(p2, wy0 + 3, a2);   // r6 -> a
    accrow(b1, b2, s1, s2, s11, s22, s12);                 // +r5
    rowvals(p1, wy0 + 4, b1); rowvals(p2, wy0 + 4, b2);   // r7 -> b
    accrow(a1, a2, s1, s2, s11, s22, s12);                 // +r6  (window r0..r6)
    rowvals(p1, wy0 - 3, c1); rowvals(p2, wy0 - 3, c2);   // leave0 (r0) -> c

    float acc = rowssim(s1, s2, s11, s22, s12, lane);      // row wy0

    accrow(b1, b2, s1, s2, s11, s22, s12);                 // +r7
    rowvals(p1, wy0 + 5, b1); rowvals(p2, wy0 + 5, b2);   // r8 -> b
    subrow(c1, c2, s1, s2, s11, s22, s12);                 // -r0  (window r1..r7)
    rowvals(p1, wy0 - 2, c1); rowvals(p2, wy0 - 2, c2);   // leave1 (r1) -> c

    acc += rowssim(s1, s2, s11, s22, s12, lane);           // row wy0+1

    accrow(b1, b2, s1, s2, s11, s22, s12);                 // +r8
    rowvals(p1, wy0 + 6, b1); rowvals(p2, wy0 + 6, b2);   // r9 -> b
    subrow(c1, c2, s1, s2, s11, s22, s12);                 // -r1  (window r2..r8)
    rowvals(p1, wy0 - 1, c1); rowvals(p2, wy0 - 1, c2);   // leave2 (r2) -> c

    acc += rowssim(s1, s2, s11, s22, s12, lane);           // row wy0+2

    accrow(b1, b2, s1, s2, s11, s22, s12);                 // +r9
    subrow(c1, c2, s1, s2, s11, s22, s12);                 // -r2  (window r3..r9)

    acc += rowssim(s1, s2, s11, s22, s12, lane);           // row wy0+3

    // block reduction: wave shuffle-reduce then LDS across 4 waves
    #pragma unroll
    for (int off = 32; off; off >>= 1) acc += __shfl_down(acc, off, 64);

    __shared__ float red[NWAVE];
    if (lane == 0) red[wv] = acc;
    __syncthreads();
    if (tid == 0) {
        partials[bid] = (red[0] + red[1]) + (red[2] + red[3]);
    }
}

extern "C" __global__ void __launch_bounds__(64)
ssim_final(const float* __restrict__ partials, float* __restrict__ out)
{
    const int lane = threadIdx.x;
    double s = 0.0;
    #pragma unroll
    for (int i = 0; i < NBLK / 64; ++i) s += (double)partials[lane + (i << 6)];
    #pragma unroll
    for (int off = 32; off; off >>= 1) s += __shfl_down(s, off, 64);
    if (lane == 0) {
        out[0] = (float)(1.0 - s / ((double)NIMG * IMG_H * IMG_W));
    }
}

extern "C" void kernel_launch(void* const* d_in, const int* in_sizes, int n_in,
                              void* d_out, int out_size, void* d_ws, size_t ws_size,
                              hipStream_t stream) {
    const float* img1 = (const float*)d_in[0];
    const float* img2 = (const float*)d_in[1];
    float* partials = (float*)d_ws;   // NBLK floats

    hipLaunchKernelGGL(ssim_main, dim3(NBLK), dim3(256), 0, stream,
                       img1, img2, partials);
    hipLaunchKernelGGL(ssim_final, dim3(1), dim3(64), 0, stream,
                       partials, (float*)d_out);
}

// Round 6
// 35.708 us; speedup vs baseline: 2.1345x; 2.1345x over previous
//
#include <hip/hip_runtime.h>

#define IMG_H 512
#define IMG_W 512
#define NIMG  32
#define RPW   2                      // output rows per wave
#define NWAVE 4                      // waves per block
#define ROWS_PER_BLOCK (RPW * NWAVE) // 8
#define STRIPS (IMG_H / ROWS_PER_BLOCK) // 64 strips per image
#define NBLK (NIMG * STRIPS)         // 2048 blocks

__device__ __forceinline__ float sh_up(float v, int lane) {
    float t = __shfl_up(v, 1, 64);
    return lane == 0 ? 0.f : t;
}
__device__ __forceinline__ float sh_dn(float v, int lane) {
    float t = __shfl_down(v, 1, 64);
    return lane == 63 ? 0.f : t;
}

// load one row's 8 columns for this lane (zeros outside the image)
__device__ __forceinline__ void rowvals(const float* __restrict__ p, int y, float* x) {
    if ((unsigned)y < (unsigned)IMG_H) {
        const float4* q = (const float4*)(p + (size_t)y * IMG_W);
        float4 a = q[0], b = q[1];
        x[0] = a.x; x[1] = a.y; x[2] = a.z; x[3] = a.w;
        x[4] = b.x; x[5] = b.y; x[6] = b.z; x[7] = b.w;
    } else {
        #pragma unroll
        for (int k = 0; k < 8; ++k) x[k] = 0.f;
    }
}

__device__ __forceinline__ void accrow(const float* x1, const float* x2,
        float* s1, float* s2, float* s11, float* s22, float* s12) {
    #pragma unroll
    for (int k = 0; k < 8; ++k) {
        s1[k] += x1[k]; s2[k] += x2[k];
        s11[k] = fmaf(x1[k], x1[k], s11[k]);
        s22[k] = fmaf(x2[k], x2[k], s22[k]);
        s12[k] = fmaf(x1[k], x2[k], s12[k]);
    }
}
__device__ __forceinline__ void subrow(const float* x1, const float* x2,
        float* s1, float* s2, float* s11, float* s22, float* s12) {
    #pragma unroll
    for (int k = 0; k < 8; ++k) {
        s1[k] -= x1[k]; s2[k] -= x2[k];
        s11[k] = fmaf(-x1[k], x1[k], s11[k]);
        s22[k] = fmaf(-x2[k], x2[k], s22[k]);
        s12[k] = fmaf(-x1[k], x2[k], s12[k]);
    }
}

// horizontal 7-box-sum: v[0..7] = this lane's 8 column values (vertical sums),
// halo via lane+-1 shuffles, sliding-window in registers.
__device__ __forceinline__ void hbox(const float* v, float* h, int lane) {
    float l5 = sh_up(v[5], lane), l6 = sh_up(v[6], lane), l7 = sh_up(v[7], lane);
    float r0 = sh_dn(v[0], lane), r1 = sh_dn(v[1], lane), r2 = sh_dn(v[2], lane);
    h[0] = ((l5 + l6) + (l7 + v[0])) + ((v[1] + v[2]) + v[3]);
    h[1] = h[0] - l5   + v[4];
    h[2] = h[1] - l6   + v[5];
    h[3] = h[2] - l7   + v[6];
    h[4] = h[3] - v[0] + v[7];
    h[5] = h[4] - v[1] + r0;
    h[6] = h[5] - v[2] + r1;
    h[7] = h[6] - v[3] + r2;
}

// one output row: horizontal sums + SSIM formula, returns partial sum
__device__ __forceinline__ float rowssim(const float* s1, const float* s2,
        const float* s11, const float* s22, const float* s12, int lane) {
    constexpr float C1f = 1e-4f;   // (0.01)^2
    constexpr float C2f = 9e-4f;   // (0.03)^2
    float h1[8], h2[8], h11[8], h22[8], h12[8];
    hbox(s1,  h1,  lane);
    hbox(s2,  h2,  lane);
    hbox(s11, h11, lane);
    hbox(s22, h22, lane);
    hbox(s12, h12, lane);
    float acc = 0.f;
    #pragma unroll
    for (int k = 0; k < 8; ++k) {
        const float mu1 = h1[k], mu2 = h2[k];
        const float mu11 = mu1 * mu1, mu22 = mu2 * mu2, mu12 = mu1 * mu2;
        const float sg1  = h11[k] - mu11;
        const float sg2  = h22[k] - mu22;
        const float sg12 = h12[k] - mu12;
        const float num = (2.f * mu12 + C1f) * (2.f * sg12 + C2f);
        const float den = (mu11 + mu22 + C1f) * (sg1 + sg2 + C2f);
        float r = __builtin_amdgcn_rcpf(den);
        r = r * (2.0f - den * r);          // den > 0 always; 1 Newton step
        acc = fmaf(num, r, acc);
    }
    return acc;
}

extern "C" __global__ void __launch_bounds__(256, 4)
ssim_main(const float* __restrict__ img1, const float* __restrict__ img2,
          float* __restrict__ partials)
{
    const int tid  = threadIdx.x;
    const int lane = tid & 63;
    const int wv   = tid >> 6;

    // XCD-aware swizzle: 2048 blocks, 8 XCDs -> each XCD gets 4 whole images
    const int bid   = blockIdx.x;
    const int xcd   = bid & 7;
    const int idx   = bid >> 3;           // 0..255
    const int img   = xcd * (NIMG / 8) + (idx >> 6);
    const int strip = idx & 63;
    const int wy0   = strip * ROWS_PER_BLOCK + wv * RPW;

    const size_t base = (size_t)img * (IMG_H * IMG_W) + (size_t)(lane << 3);
    const float* p1 = img1 + base;
    const float* p2 = img2 + base;

    // Window rows: q0=wy0-3 .. q7=wy0+4.
    // Output row wy0   = box over q0..q6
    // Output row wy0+1 = box over q1..q7
    // Load order q1..q6, q0, q7 with 3 rotating buffers (A,B,C): q0 is added
    // last, then SUBTRACTED from registers (no re-load) and q7 added.
    float A1[8], A2[8], B1[8], B2[8], Cx1[8], Cx2[8];

    rowvals(p1, wy0 - 2, A1); rowvals(p2, wy0 - 2, A2);   // q1 -> A
    rowvals(p1, wy0 - 1, B1); rowvals(p2, wy0 - 1, B2);   // q2 -> B
    rowvals(p1, wy0 + 0, Cx1); rowvals(p2, wy0 + 0, Cx2); // q3 -> C

    float s1[8], s2[8], s11[8], s22[8], s12[8];
    #pragma unroll
    for (int k = 0; k < 8; ++k) { s1[k] = s2[k] = s11[k] = s22[k] = s12[k] = 0.f; }

    accrow(A1, A2, s1, s2, s11, s22, s12);                // +q1
    rowvals(p1, wy0 + 1, A1); rowvals(p2, wy0 + 1, A2);   // q4 -> A
    accrow(B1, B2, s1, s2, s11, s22, s12);                // +q2
    rowvals(p1, wy0 + 2, B1); rowvals(p2, wy0 + 2, B2);   // q5 -> B
    accrow(Cx1, Cx2, s1, s2, s11, s22, s12);              // +q3
    rowvals(p1, wy0 + 3, Cx1); rowvals(p2, wy0 + 3, Cx2); // q6 -> C
    accrow(A1, A2, s1, s2, s11, s22, s12);                // +q4
    rowvals(p1, wy0 - 3, A1); rowvals(p2, wy0 - 3, A2);   // q0 -> A
    accrow(B1, B2, s1, s2, s11, s22, s12);                // +q5
    rowvals(p1, wy0 + 4, B1); rowvals(p2, wy0 + 4, B2);   // q7 -> B
    accrow(Cx1, Cx2, s1, s2, s11, s22, s12);              // +q6
    accrow(A1, A2, s1, s2, s11, s22, s12);                // +q0 (window q0..q6)

    float acc = rowssim(s1, s2, s11, s22, s12, lane);     // row wy0

    subrow(A1, A2, s1, s2, s11, s22, s12);                // -q0
    accrow(B1, B2, s1, s2, s11, s22, s12);                // +q7 (window q1..q7)

    acc += rowssim(s1, s2, s11, s22, s12, lane);          // row wy0+1

    // block reduction: wave shuffle-reduce then LDS across 4 waves
    #pragma unroll
    for (int off = 32; off; off >>= 1) acc += __shfl_down(acc, off, 64);

    __shared__ float red[NWAVE];
    if (lane == 0) red[wv] = acc;
    __syncthreads();
    if (tid == 0) {
        partials[bid] = (red[0] + red[1]) + (red[2] + red[3]);
    }
}

extern "C" __global__ void __launch_bounds__(64)
ssim_final(const float* __restrict__ partials, float* __restrict__ out)
{
    const int lane = threadIdx.x;
    double s = 0.0;
    #pragma unroll
    for (int i = 0; i < NBLK / 64; ++i) s += (double)partials[lane + (i << 6)];
    #pragma unroll
    for (int off = 32; off; off >>= 1) s += __shfl_down(s, off, 64);
    if (lane == 0) {
        out[0] = (float)(1.0 - s / ((double)NIMG * IMG_H * IMG_W));
    }
}

extern "C" void kernel_launch(void* const* d_in, const int* in_sizes, int n_in,
                              void* d_out, int out_size, void* d_ws, size_t ws_size,
                              hipStream_t stream) {
    const float* img1 = (const float*)d_in[0];
    const float* img2 = (const float*)d_in[1];
    float* partials = (float*)d_ws;   // NBLK floats

    hipLaunchKernelGGL(ssim_main, dim3(NBLK), dim3(256), 0, stream,
                       img1, img2, partials);
    hipLaunchKernelGGL(ssim_final, dim3(1), dim3(64), 0, stream,
                       partials, (float*)d_out);
}

// Round 7
// 24.300 us; speedup vs baseline: 3.1364x; 1.4694x over previous
//
#include <hip/hip_runtime.h>

#define IMG_H 512
#define IMG_W 512
#define NIMG  32
#define RPW   2                      // output rows per wave
#define NWAVE 4                      // waves per block
#define ROWS_PER_BLOCK (RPW * NWAVE) // 8
#define STRIPS (IMG_H / ROWS_PER_BLOCK) // 64 strips per image
#define NBLK (NIMG * STRIPS)         // 2048 blocks

__device__ __forceinline__ float sh_up(float v, int lane) {
    float t = __shfl_up(v, 1, 64);
    return lane == 0 ? 0.f : t;
}
__device__ __forceinline__ float sh_dn(float v, int lane) {
    float t = __shfl_down(v, 1, 64);
    return lane == 63 ? 0.f : t;
}

// load one row's 8 columns for this lane (zeros outside the image)
__device__ __forceinline__ void rowvals(const float* __restrict__ p, int y, float* x) {
    if ((unsigned)y < (unsigned)IMG_H) {
        const float4* q = (const float4*)(p + (size_t)y * IMG_W);
        float4 a = q[0], b = q[1];
        x[0] = a.x; x[1] = a.y; x[2] = a.z; x[3] = a.w;
        x[4] = b.x; x[5] = b.y; x[6] = b.z; x[7] = b.w;
    } else {
        #pragma unroll
        for (int k = 0; k < 8; ++k) x[k] = 0.f;
    }
}

__device__ __forceinline__ void accrow(const float* x1, const float* x2,
        float* s1, float* s2, float* s11, float* s22, float* s12) {
    #pragma unroll
    for (int k = 0; k < 8; ++k) {
        s1[k] += x1[k]; s2[k] += x2[k];
        s11[k] = fmaf(x1[k], x1[k], s11[k]);
        s22[k] = fmaf(x2[k], x2[k], s22[k]);
        s12[k] = fmaf(x1[k], x2[k], s12[k]);
    }
}
__device__ __forceinline__ void subrow(const float* x1, const float* x2,
        float* s1, float* s2, float* s11, float* s22, float* s12) {
    #pragma unroll
    for (int k = 0; k < 8; ++k) {
        s1[k] -= x1[k]; s2[k] -= x2[k];
        s11[k] = fmaf(-x1[k], x1[k], s11[k]);
        s22[k] = fmaf(-x2[k], x2[k], s22[k]);
        s12[k] = fmaf(-x1[k], x2[k], s12[k]);
    }
}

// horizontal 7-box-sum: v[0..7] = this lane's 8 column values (vertical sums),
// halo via lane+-1 shuffles, sliding-window in registers.
__device__ __forceinline__ void hbox(const float* v, float* h, int lane) {
    float l5 = sh_up(v[5], lane), l6 = sh_up(v[6], lane), l7 = sh_up(v[7], lane);
    float r0 = sh_dn(v[0], lane), r1 = sh_dn(v[1], lane), r2 = sh_dn(v[2], lane);
    h[0] = ((l5 + l6) + (l7 + v[0])) + ((v[1] + v[2]) + v[3]);
    h[1] = h[0] - l5   + v[4];
    h[2] = h[1] - l6   + v[5];
    h[3] = h[2] - l7   + v[6];
    h[4] = h[3] - v[0] + v[7];
    h[5] = h[4] - v[1] + r0;
    h[6] = h[5] - v[2] + r1;
    h[7] = h[6] - v[3] + r2;
}

// one output row: horizontal sums + SSIM formula, returns partial sum
__device__ __forceinline__ float rowssim(const float* s1, const float* s2,
        const float* s11, const float* s22, const float* s12, int lane) {
    constexpr float C1f = 1e-4f;   // (0.01)^2
    constexpr float C2f = 9e-4f;   // (0.03)^2
    float h1[8], h2[8], h11[8], h22[8], h12[8];
    hbox(s1,  h1,  lane);
    hbox(s2,  h2,  lane);
    hbox(s11, h11, lane);
    hbox(s22, h22, lane);
    hbox(s12, h12, lane);
    float acc = 0.f;
    #pragma unroll
    for (int k = 0; k < 8; ++k) {
        const float mu1 = h1[k], mu2 = h2[k];
        const float mu11 = mu1 * mu1, mu22 = mu2 * mu2, mu12 = mu1 * mu2;
        const float sg1  = h11[k] - mu11;
        const float sg2  = h22[k] - mu22;
        const float sg12 = h12[k] - mu12;
        const float num = (2.f * mu12 + C1f) * (2.f * sg12 + C2f);
        const float den = (mu11 + mu22 + C1f) * (sg1 + sg2 + C2f);
        float r = __builtin_amdgcn_rcpf(den);
        r = r * (2.0f - den * r);          // den > 0 always; 1 Newton step
        acc = fmaf(num, r, acc);
    }
    return acc;
}

extern "C" __global__ void __launch_bounds__(256, 2)
ssim_main(const float* __restrict__ img1, const float* __restrict__ img2,
          float* __restrict__ partials)
{
    const int tid  = threadIdx.x;
    const int lane = tid & 63;
    const int wv   = tid >> 6;

    // XCD-aware swizzle: 2048 blocks, 8 XCDs -> each XCD gets 4 whole images
    const int bid   = blockIdx.x;
    const int xcd   = bid & 7;
    const int idx   = bid >> 3;           // 0..255
    const int img   = xcd * (NIMG / 8) + (idx >> 6);
    const int strip = idx & 63;
    const int wy0   = strip * ROWS_PER_BLOCK + wv * RPW;

    const size_t base = (size_t)img * (IMG_H * IMG_W) + (size_t)(lane << 3);
    const float* p1 = img1 + base;
    const float* p2 = img2 + base;

    // Window rows q0..q7 = wy0-3 .. wy0+4.
    //   output row wy0   = box over q0..q6
    //   output row wy0+1 = box over q1..q7
    // ALL 8 row-pair loads are issued upfront into distinct statically-indexed
    // buffers -> compiler emits one 32-wide global_load burst and descending
    // vmcnt waits: a single latency exposure per wave instead of eight.
    float b0a[8], b0b[8], b1a[8], b1b[8], b2a[8], b2b[8], b3a[8], b3b[8];
    float b4a[8], b4b[8], b5a[8], b5b[8], b6a[8], b6b[8], b7a[8], b7b[8];

    rowvals(p1, wy0 - 3, b0a); rowvals(p2, wy0 - 3, b0b);
    rowvals(p1, wy0 - 2, b1a); rowvals(p2, wy0 - 2, b1b);
    rowvals(p1, wy0 - 1, b2a); rowvals(p2, wy0 - 1, b2b);
    rowvals(p1, wy0 + 0, b3a); rowvals(p2, wy0 + 0, b3b);
    rowvals(p1, wy0 + 1, b4a); rowvals(p2, wy0 + 1, b4b);
    rowvals(p1, wy0 + 2, b5a); rowvals(p2, wy0 + 2, b5b);
    rowvals(p1, wy0 + 3, b6a); rowvals(p2, wy0 + 3, b6b);
    rowvals(p1, wy0 + 4, b7a); rowvals(p2, wy0 + 4, b7b);

    float s1[8], s2[8], s11[8], s22[8], s12[8];
    #pragma unroll
    for (int k = 0; k < 8; ++k) { s1[k] = s2[k] = s11[k] = s22[k] = s12[k] = 0.f; }

    accrow(b0a, b0b, s1, s2, s11, s22, s12);   // +q0
    accrow(b1a, b1b, s1, s2, s11, s22, s12);   // +q1
    accrow(b2a, b2b, s1, s2, s11, s22, s12);   // +q2
    accrow(b3a, b3b, s1, s2, s11, s22, s12);   // +q3
    accrow(b4a, b4b, s1, s2, s11, s22, s12);   // +q4
    accrow(b5a, b5b, s1, s2, s11, s22, s12);   // +q5
    accrow(b6a, b6b, s1, s2, s11, s22, s12);   // +q6  (window q0..q6)

    float acc = rowssim(s1, s2, s11, s22, s12, lane);     // row wy0

    subrow(b0a, b0b, s1, s2, s11, s22, s12);   // -q0
    accrow(b7a, b7b, s1, s2, s11, s22, s12);   // +q7  (window q1..q7)

    acc += rowssim(s1, s2, s11, s22, s12, lane);          // row wy0+1

    // block reduction: wave shuffle-reduce then LDS across 4 waves
    #pragma unroll
    for (int off = 32; off; off >>= 1) acc += __shfl_down(acc, off, 64);

    __shared__ float red[NWAVE];
    if (lane == 0) red[wv] = acc;
    __syncthreads();
    if (tid == 0) {
        partials[bid] = (red[0] + red[1]) + (red[2] + red[3]);
    }
}

extern "C" __global__ void __launch_bounds__(64)
ssim_final(const float* __restrict__ partials, float* __restrict__ out)
{
    const int lane = threadIdx.x;
    double s = 0.0;
    #pragma unroll
    for (int i = 0; i < NBLK / 64; ++i) s += (double)partials[lane + (i << 6)];
    #pragma unroll
    for (int off = 32; off; off >>= 1) s += __shfl_down(s, off, 64);
    if (lane == 0) {
        out[0] = (float)(1.0 - s / ((double)NIMG * IMG_H * IMG_W));
    }
}

extern "C" void kernel_launch(void* const* d_in, const int* in_sizes, int n_in,
                              void* d_out, int out_size, void* d_ws, size_t ws_size,
                              hipStream_t stream) {
    const float* img1 = (const float*)d_in[0];
    const float* img2 = (const float*)d_in[1];
    float* partials = (float*)d_ws;   // NBLK floats

    hipLaunchKernelGGL(ssim_main, dim3(NBLK), dim3(256), 0, stream,
                       img1, img2, partials);
    hipLaunchKernelGGL(ssim_final, dim3(1), dim3(64), 0, stream,
                       partials, (float*)d_out);
}